// Round 1
// baseline (534.945 us; speedup 1.0000x reference)
//
#include <hip/hip_runtime.h>
#include <hip/hip_bf16.h>

typedef __bf16 bf16;
typedef bf16 bf16x2 __attribute__((ext_vector_type(2)));
typedef bf16 bf16x4 __attribute__((ext_vector_type(4)));
typedef bf16 bf16x8 __attribute__((ext_vector_type(8)));
typedef float f32x4 __attribute__((ext_vector_type(4)));

__device__ __forceinline__ void gload_lds16(const void* g, void* l) {
  __builtin_amdgcn_global_load_lds((__attribute__((address_space(1))) void*)g,
                                   (__attribute__((address_space(3))) void*)l,
                                   16, 0, 0);
}

// ---------------- prep kernels ----------------

__global__ void cast_f32_to_bf16(const float* __restrict__ in, bf16* __restrict__ out, int n4) {
  int i = blockIdx.x * blockDim.x + threadIdx.x;
  if (i >= n4) return;
  float4 v = ((const float4*)in)[i];
  bf16x4 o = {(bf16)v.x, (bf16)v.y, (bf16)v.z, (bf16)v.w};
  ((bf16x4*)out)[i] = o;
}

__global__ void concat_bias(const float* __restrict__ ub, const float* __restrict__ vb,
                            float* __restrict__ buv) {
  int i = blockIdx.x * blockDim.x + threadIdx.x;
  if (i < 1024) { buv[i] = ub[i]; buv[1024 + i] = vb[i]; }
}

// Dense Toeplitz kernel table: Tk[h][lag+63][d], lag in [-63,63], f32.
__global__ void build_tk(const float* __restrict__ zero, const float* __restrict__ pa,
                         const float* __restrict__ pb, const float* __restrict__ na,
                         const float* __restrict__ nb, float* __restrict__ Tk) {
  int idx = blockIdx.x * blockDim.x + threadIdx.x;
  if (idx >= 8 * 127 * 128) return;
  int d = idx & 127;
  int rest = idx >> 7;
  int lagIdx = rest % 127;
  int h = rest / 127;
  int lag = lagIdx - 63;
  float val;
  if (lag == 0) {
    val = zero[h * 128 + d];
  } else {
    int k = (lag > 0) ? lag : -lag;
    const float* A  = (lag > 0) ? pa : na;
    const float* Bm = (lag > 0) ? pb : nb;
    float pos_f = (float)(k - 1) * (15.0f / 62.0f);
    int lo = (int)floorf(pos_f);
    int hi = min(lo + 1, 15);
    float w = pos_f - (float)lo;
    float s = 0.f;
    for (int r = 0; r < 32; ++r) {
      float c = (1.f - w) * A[(h * 16 + lo) * 32 + r] + w * A[(h * 16 + hi) * 32 + r];
      s += c * Bm[(h * 32 + r) * 128 + d];
    }
    val = s * powf(0.999f, (float)k);
  }
  Tk[idx] = val;
}

// ---------------- GEMM (m97-style 128x128, B^T input) ----------------
// MODE 0: bias+silu, bf16 out split into u (cols<1024) / v (cols>=1024), stride 1024
// MODE 1: bias only, f32 out, stride N

template<int MODE>
__global__ __launch_bounds__(256)
void gemm_bt(const bf16* __restrict__ A, const bf16* __restrict__ B,
             const float* __restrict__ bias,
             bf16* __restrict__ out_u, bf16* __restrict__ out_v,
             float* __restrict__ out_f,
             int M, int N, int K) {
  __shared__ bf16 As[128 * 32];
  __shared__ bf16 Bs[128 * 32];
  const int tid  = threadIdx.x;
  const int lane = tid & 63;
  const int nbn  = N >> 7;
  const int br   = (blockIdx.x / nbn) << 7;
  const int bc   = (blockIdx.x % nbn) << 7;
  const int wub  = __builtin_amdgcn_readfirstlane(tid & 192);  // wave*64, uniform

  f32x4 acc[4][4] = {};

  auto stage = [&](int k0) {
#pragma unroll
    for (int r = 0; r < 2; ++r) {
      const int flat = r * 256 + tid;
      const int row  = flat >> 2;
      const int kc   = (flat & 3) << 3;   // 8-elem chunk within the 32-wide k
      gload_lds16(A + ((size_t)(br + row) * K + k0 + kc),
                  (char*)As + (size_t)(r * 256 + wub) * 16);
      gload_lds16(B + ((size_t)(bc + row) * K + k0 + kc),
                  (char*)Bs + (size_t)(r * 256 + wub) * 16);
    }
  };

  const int l15 = lane & 15;
  const int lk  = (lane >> 4) << 3;
  const int wr  = ((tid >> 7) & 1) << 6;
  const int wc  = ((tid >> 6) & 1) << 6;

  auto compute = [&]() {
    bf16x8 af[4], bfr[4];
#pragma unroll
    for (int m = 0; m < 4; ++m)
      af[m] = *(const bf16x8*)&As[(wr + m * 16 + l15) * 32 + lk];
#pragma unroll
    for (int n = 0; n < 4; ++n)
      bfr[n] = *(const bf16x8*)&Bs[(wc + n * 16 + l15) * 32 + lk];
#pragma unroll
    for (int m = 0; m < 4; ++m)
#pragma unroll
      for (int n = 0; n < 4; ++n)
        acc[m][n] = __builtin_amdgcn_mfma_f32_16x16x32_bf16(af[m], bfr[n], acc[m][n], 0, 0, 0);
  };

  stage(0);
  __syncthreads();
  for (int k0 = 32; k0 < K; k0 += 32) {
    compute();
    __syncthreads();
    stage(k0);
    __syncthreads();
  }
  compute();

  const int lr4 = (lane >> 4) << 2;
  if (MODE == 0) {
    const bool isU = (bc < 1024);
    bf16* outp = isU ? out_u : out_v;
#pragma unroll
    for (int m = 0; m < 4; ++m) {
#pragma unroll
      for (int n = 0; n < 4; ++n) {
        const int col  = bc + wc + n * 16 + l15;
        const int ocol = (bc & 1023) + wc + n * 16 + l15;
        const float bv = bias[col];
#pragma unroll
        for (int r = 0; r < 4; ++r) {
          const int row = br + wr + m * 16 + lr4 + r;
          float xv = acc[m][n][r] + bv;
          float s  = xv / (1.f + __expf(-xv));
          outp[(size_t)row * 1024 + ocol] = (bf16)s;
        }
      }
    }
  } else {
#pragma unroll
    for (int m = 0; m < 4; ++m) {
#pragma unroll
      for (int n = 0; n < 4; ++n) {
        const int col  = bc + wc + n * 16 + l15;
        const float bv = bias[col];
#pragma unroll
        for (int r = 0; r < 4; ++r) {
          const int row = br + wr + m * 16 + lr4 + r;
          out_f[(size_t)row * N + col] = acc[m][n][r] + bv;
        }
      }
    }
  }
}

// ---------------- Toeplitz pass (per-channel 64-tap conv along one image axis) ----
// Block: one (b, fixed-coord) row, one head. 256 thr = 4 waves; wave -> 16 output
// positions, lane -> channel pair. v row staged in LDS as f32, zero-padded in j.
// FUSE=1: out = u * 2*acc (gate fused), else out = acc. All bf16 in/out.

#define VROW 132   // 128 + 4 pad floats per j-row

template<int FUSE>
__global__ __launch_bounds__(256)
void toep_pass(const bf16* __restrict__ in, const float* __restrict__ Tk,
               const bf16* __restrict__ ufuse, bf16* __restrict__ out,
               int stride_j, int stride_row) {
  __shared__ float vbuf[96 * VROW];
  const int tid    = threadIdx.x;
  const int rowIdx = blockIdx.x >> 3;
  const int head   = blockIdx.x & 7;
  const size_t base = (size_t)(rowIdx >> 6) * 4194304
                    + (size_t)(rowIdx & 63) * stride_row + head * 128;

  // zero the j-pad rows [0,16) and [80,96)
  for (int i = tid; i < 16 * VROW; i += 256) {
    vbuf[i] = 0.f;
    vbuf[80 * VROW + i] = 0.f;
  }

  // stage the 64 x 128 bf16 row into LDS as f32 (rows 16..79)
  {
    const int j  = tid >> 2;
    const int c4 = (tid & 3) << 5;
    const bf16* p = in + base + (size_t)j * stride_j + c4;
    float* dst = &vbuf[(j + 16) * VROW + c4];
#pragma unroll
    for (int c = 0; c < 4; ++c) {
      bf16x8 a = *(const bf16x8*)(p + c * 8);
      f32x4 f0 = {(float)a[0], (float)a[1], (float)a[2], (float)a[3]};
      f32x4 f1 = {(float)a[4], (float)a[5], (float)a[6], (float)a[7]};
      *(f32x4*)(dst + c * 8)     = f0;
      *(f32x4*)(dst + c * 8 + 4) = f1;
    }
  }
  __syncthreads();

  const int lane = tid & 63;
  const int i0   = (tid >> 6) << 4;   // wave's 16-output base
  const int d0   = lane << 1;         // channel pair
  float acc0[16] = {}, acc1[16] = {};
  const float* tk  = Tk + (head * 127 + 63) * 128 + d0;  // lag 0
  const float* vb0 = &vbuf[(i0 + 16) * VROW + d0];

  for (int lag = i0 - 63; lag <= i0 + 15; ++lag) {
    const float2 t = *(const float2*)(tk + lag * 128);
    const float* vb = vb0 - lag * VROW;
#pragma unroll
    for (int ii = 0; ii < 16; ++ii) {
      const float2 vv = *(const float2*)(vb + ii * VROW);
      acc0[ii] = fmaf(t.x, vv.x, acc0[ii]);
      acc1[ii] = fmaf(t.y, vv.y, acc1[ii]);
    }
  }

#pragma unroll
  for (int ii = 0; ii < 16; ++ii) {
    const size_t oidx = base + (size_t)(i0 + ii) * stride_j + d0;
    float a0 = acc0[ii], a1 = acc1[ii];
    if (FUSE) {
      bf16x2 uu = *(const bf16x2*)(ufuse + oidx);
      a0 *= 2.f * (float)uu[0];
      a1 *= 2.f * (float)uu[1];
    }
    bf16x2 o2 = {(bf16)a0, (bf16)a1};
    *(bf16x2*)(out + oidx) = o2;
  }
}

// ---------------- launch ----------------

extern "C" void kernel_launch(void* const* d_in, const int* in_sizes, int n_in,
                              void* d_out, int out_size, void* d_ws, size_t ws_size,
                              hipStream_t stream) {
  const float* x    = (const float*)d_in[0];
  const float* u_w  = (const float*)d_in[1];
  const float* u_b  = (const float*)d_in[2];
  const float* v_w  = (const float*)d_in[3];
  const float* v_b  = (const float*)d_in[4];
  const float* o_w  = (const float*)d_in[5];
  const float* o_b  = (const float*)d_in[6];
  const float* t1z  = (const float*)d_in[7];
  const float* t1pa = (const float*)d_in[8];
  const float* t1pb = (const float*)d_in[9];
  const float* t1na = (const float*)d_in[10];
  const float* t1nb = (const float*)d_in[11];
  const float* t2z  = (const float*)d_in[12];
  const float* t2pa = (const float*)d_in[13];
  const float* t2pb = (const float*)d_in[14];
  const float* t2na = (const float*)d_in[15];
  const float* t2nb = (const float*)d_in[16];

  char* ws = (char*)d_ws;
  size_t off = 0;
  auto alloc = [&](size_t bytes) {
    char* p = ws + off;
    off += (bytes + 255) & ~(size_t)255;
    return p;
  };
  bf16*  xb   = (bf16*)alloc(32768ull * 512 * 2);     // x cast
  bf16*  wuv  = (bf16*)alloc(2048ull * 512 * 2);      // [u_w; v_w] bf16
  bf16*  owb  = (bf16*)alloc(512ull * 1024 * 2);      // o_w bf16
  float* buv  = (float*)alloc(2048ull * 4);           // [u_b; v_b]
  float* Tk1  = (float*)alloc(8ull * 127 * 128 * 4);
  float* Tk2  = (float*)alloc(8ull * 127 * 128 * 4);
  bf16*  u    = (bf16*)alloc(32768ull * 1024 * 2);    // silu(xU)
  bf16*  v    = (bf16*)alloc(32768ull * 1024 * 2);    // silu(xV)
  bf16*  tmid = (bf16*)alloc(32768ull * 1024 * 2);    // after W-mix
  bf16*  g    = v;                                    // v dead after pass1; reuse for gate

  cast_f32_to_bf16<<<16384, 256, 0, stream>>>(x, xb, 16777216 / 4);
  cast_f32_to_bf16<<<512, 256, 0, stream>>>(u_w, wuv, 524288 / 4);
  cast_f32_to_bf16<<<512, 256, 0, stream>>>(v_w, wuv + 524288, 524288 / 4);
  cast_f32_to_bf16<<<512, 256, 0, stream>>>(o_w, owb, 524288 / 4);
  concat_bias<<<4, 256, 0, stream>>>(u_b, v_b, buv);
  build_tk<<<508, 256, 0, stream>>>(t1z, t1pa, t1pb, t1na, t1nb, Tk1);
  build_tk<<<508, 256, 0, stream>>>(t2z, t2pa, t2pb, t2na, t2nb, Tk2);

  // u,v = silu(x @ [Wu;Wv]^T + b)
  gemm_bt<0><<<4096, 256, 0, stream>>>(xb, wuv, buv, u, v, nullptr, 32768, 2048, 512);
  // W-axis mix (t1): rows (b,i_h), j stride 1024
  toep_pass<0><<<4096, 256, 0, stream>>>(v, Tk1, nullptr, tmid, 1024, 65536);
  // H-axis mix (t2): rows (b,i_w), j stride 65536; fuse g = u * 2*acc
  toep_pass<1><<<4096, 256, 0, stream>>>(tmid, Tk2, u, g, 65536, 1024);
  // out = g @ o_w^T + o_b  (f32)
  gemm_bt<1><<<1024, 256, 0, stream>>>(g, owb, o_b, nullptr, nullptr, (float*)d_out,
                                       32768, 512, 1024);
}

// Round 2
// 395.690 us; speedup vs baseline: 1.3519x; 1.3519x over previous
//
#include <hip/hip_runtime.h>
#include <hip/hip_bf16.h>
#include <hip/hip_fp16.h>

typedef __bf16 bf16;
typedef bf16 bf16x2 __attribute__((ext_vector_type(2)));
typedef bf16 bf16x4 __attribute__((ext_vector_type(4)));
typedef bf16 bf16x8 __attribute__((ext_vector_type(8)));
typedef float f32x2 __attribute__((ext_vector_type(2)));
typedef float f32x4 __attribute__((ext_vector_type(4)));

__device__ __forceinline__ void gload_lds16(const void* g, void* l) {
  __builtin_amdgcn_global_load_lds((__attribute__((address_space(1))) void*)g,
                                   (__attribute__((address_space(3))) void*)l,
                                   16, 0, 0);
}

__device__ __forceinline__ f32x2 fma2(f32x2 a, f32x2 b, f32x2 c) {
  return __builtin_elementwise_fma(a, b, c);   // -> v_pk_fma_f32
}

__device__ __forceinline__ f32x2 cvt2(unsigned int u) {
  __half2 h = *(__half2*)&u;
  float2 f = __half22float2(h);
  f32x2 r = {f.x, f.y};
  return r;
}

// ---------------- prep kernels ----------------

__global__ void cast_f32_to_bf16(const float* __restrict__ in, bf16* __restrict__ out, int n4) {
  int i = blockIdx.x * blockDim.x + threadIdx.x;
  if (i >= n4) return;
  float4 v = ((const float4*)in)[i];
  bf16x4 o = {(bf16)v.x, (bf16)v.y, (bf16)v.z, (bf16)v.w};
  ((bf16x4*)out)[i] = o;
}

__global__ void concat_bias(const float* __restrict__ ub, const float* __restrict__ vb,
                            float* __restrict__ buv) {
  int i = blockIdx.x * blockDim.x + threadIdx.x;
  if (i < 1024) { buv[i] = ub[i]; buv[1024 + i] = vb[i]; }
}

// Toeplitz table, f16 channel-pair packed: Tkp[h][lag+63][cpair] (u32 = 2 f16).
__global__ void build_tkp(const float* __restrict__ zero, const float* __restrict__ pa,
                          const float* __restrict__ pb, const float* __restrict__ na,
                          const float* __restrict__ nb, unsigned int* __restrict__ Tkp,
                          float scale) {
  int idx = blockIdx.x * blockDim.x + threadIdx.x;
  if (idx >= 8 * 127 * 64) return;
  int cp = idx & 63;
  int lagIdx = (idx >> 6) % 127;
  int h = idx / (64 * 127);
  int lag = lagIdx - 63;
  float t0, t1;
  if (lag == 0) {
    t0 = zero[h * 128 + 2 * cp];
    t1 = zero[h * 128 + 2 * cp + 1];
  } else {
    int k = lag > 0 ? lag : -lag;
    const float* A  = lag > 0 ? pa : na;
    const float* Bm = lag > 0 ? pb : nb;
    float pos_f = (float)(k - 1) * (15.0f / 62.0f);
    int lo = (int)floorf(pos_f);
    int hi = min(lo + 1, 15);
    float w = pos_f - (float)lo;
    float s0 = 0.f, s1 = 0.f;
    for (int r = 0; r < 32; ++r) {
      float c = (1.f - w) * A[(h * 16 + lo) * 32 + r] + w * A[(h * 16 + hi) * 32 + r];
      s0 += c * Bm[(h * 32 + r) * 128 + 2 * cp];
      s1 += c * Bm[(h * 32 + r) * 128 + 2 * cp + 1];
    }
    float dec = powf(0.999f, (float)k);
    t0 = s0 * dec;
    t1 = s1 * dec;
  }
  __half2 hv = __floats2half2_rn(t0 * scale, t1 * scale);
  Tkp[idx] = *(unsigned int*)&hv;
}

// ---------------- GEMM (m97-style 128x128, B^T input) ----------------

template<int MODE>
__global__ __launch_bounds__(256)
void gemm_bt(const bf16* __restrict__ A, const bf16* __restrict__ B,
             const float* __restrict__ bias,
             bf16* __restrict__ out_u, bf16* __restrict__ out_v,
             float* __restrict__ out_f,
             int M, int N, int K) {
  __shared__ bf16 As[128 * 32];
  __shared__ bf16 Bs[128 * 32];
  const int tid  = threadIdx.x;
  const int lane = tid & 63;
  const int nbn  = N >> 7;
  const int br   = (blockIdx.x / nbn) << 7;
  const int bc   = (blockIdx.x % nbn) << 7;
  const int wub  = __builtin_amdgcn_readfirstlane(tid & 192);

  f32x4 acc[4][4] = {};

  auto stage = [&](int k0) {
#pragma unroll
    for (int r = 0; r < 2; ++r) {
      const int flat = r * 256 + tid;
      const int row  = flat >> 2;
      const int kc   = (flat & 3) << 3;
      gload_lds16(A + ((size_t)(br + row) * K + k0 + kc),
                  (char*)As + (size_t)(r * 256 + wub) * 16);
      gload_lds16(B + ((size_t)(bc + row) * K + k0 + kc),
                  (char*)Bs + (size_t)(r * 256 + wub) * 16);
    }
  };

  const int l15 = lane & 15;
  const int lk  = (lane >> 4) << 3;
  const int wr  = ((tid >> 7) & 1) << 6;
  const int wc  = ((tid >> 6) & 1) << 6;

  auto compute = [&]() {
    bf16x8 af[4], bfr[4];
#pragma unroll
    for (int m = 0; m < 4; ++m)
      af[m] = *(const bf16x8*)&As[(wr + m * 16 + l15) * 32 + lk];
#pragma unroll
    for (int n = 0; n < 4; ++n)
      bfr[n] = *(const bf16x8*)&Bs[(wc + n * 16 + l15) * 32 + lk];
#pragma unroll
    for (int m = 0; m < 4; ++m)
#pragma unroll
      for (int n = 0; n < 4; ++n)
        acc[m][n] = __builtin_amdgcn_mfma_f32_16x16x32_bf16(af[m], bfr[n], acc[m][n], 0, 0, 0);
  };

  stage(0);
  __syncthreads();
  for (int k0 = 32; k0 < K; k0 += 32) {
    compute();
    __syncthreads();
    stage(k0);
    __syncthreads();
  }
  compute();

  const int lr4 = (lane >> 4) << 2;
  if (MODE == 0) {
    const bool isU = (bc < 1024);
    bf16* outp = isU ? out_u : out_v;
#pragma unroll
    for (int m = 0; m < 4; ++m) {
#pragma unroll
      for (int n = 0; n < 4; ++n) {
        const int col  = bc + wc + n * 16 + l15;
        const int ocol = (bc & 1023) + wc + n * 16 + l15;
        const float bv = bias[col];
#pragma unroll
        for (int r = 0; r < 4; ++r) {
          const int row = br + wr + m * 16 + lr4 + r;
          float xv = acc[m][n][r] + bv;
          float s  = xv / (1.f + __expf(-xv));
          outp[(size_t)row * 1024 + ocol] = (bf16)s;
        }
      }
    }
  } else {
#pragma unroll
    for (int m = 0; m < 4; ++m) {
#pragma unroll
      for (int n = 0; n < 4; ++n) {
        const int col  = bc + wc + n * 16 + l15;
        const float bv = bias[col];
#pragma unroll
        for (int r = 0; r < 4; ++r) {
          const int row = br + wr + m * 16 + lr4 + r;
          out_f[(size_t)row * N + col] = acc[m][n][r] + bv;
        }
      }
    }
  }
}

// ---------------- Toeplitz pass: register-ring sliding-window conv -------------
// Block: one image row (64 positions) x one head (128 ch). 4 waves, wave w owns
// i in [16w, 16w+16); lane owns channel pair d0=2*lane. Per j-step: 1 v read +
// 1 T-ring refill + 16 v_pk_fma_f32 (32 MAC). T table f16-packed, staged in LDS.

template<int FUSE>
__global__ __launch_bounds__(256)
void toep_pass(const bf16* __restrict__ in, const unsigned int* __restrict__ Tkp,
               const bf16* __restrict__ ufuse, bf16* __restrict__ out,
               int stride_j, int stride_row) {
  __shared__ bf16 vbuf[64 * 132];          // pad row to 132 bf16 (staging-conflict fix)
  __shared__ unsigned int tkl[127 * 64];   // head's T table, f16x2 per u32
  const int tid    = threadIdx.x;
  const int rowIdx = blockIdx.x >> 3;
  const int head   = blockIdx.x & 7;
  const size_t base = (size_t)(rowIdx >> 6) * 4194304
                    + (size_t)(rowIdx & 63) * stride_row + head * 128;

  // stage T table (8128 u32, coalesced)
  {
    const unsigned int* tg = Tkp + head * 8128;
    for (int idx = tid; idx < 8128; idx += 256) tkl[idx] = tg[idx];
  }
  // stage v row: 512 chunks of 16 ch
#pragma unroll
  for (int it = 0; it < 2; ++it) {
    int c  = it * 256 + tid;
    int j  = c >> 3;
    int cg = c & 7;
    const bf16* p = in + base + (size_t)j * stride_j + cg * 16;
    bf16x8 a0 = *(const bf16x8*)p;
    bf16x8 a1 = *(const bf16x8*)(p + 8);
    *(bf16x8*)&vbuf[j * 132 + cg * 16]     = a0;
    *(bf16x8*)&vbuf[j * 132 + cg * 16 + 8] = a1;
  }
  __syncthreads();

  const int lane = tid & 63;
  const int i0   = (tid >> 6) << 4;
  f32x2 acc[16] = {};
  f32x2 tr[79];                     // s = lag - (i0-63); window at j: s in [63-j, 78-j]
#pragma unroll
  for (int s = 61; s < 79; ++s) tr[s] = cvt2(tkl[(i0 + s) * 64 + lane]);

#pragma unroll
  for (int j = 0; j < 64; ++j) {
    unsigned int vu = *(const unsigned int*)&vbuf[j * 132 + (lane << 1)];
    f32x2 v2;
    v2.x = __uint_as_float(vu << 16);
    v2.y = __uint_as_float(vu & 0xFFFF0000u);
#pragma unroll
    for (int ii = 0; ii < 16; ++ii)
      acc[ii] = fma2(tr[ii - j + 63], v2, acc[ii]);
    if (j <= 60) tr[60 - j] = cvt2(tkl[(i0 + 60 - j) * 64 + lane]);  // static guard
  }

  const int d0 = lane << 1;
#pragma unroll
  for (int ii = 0; ii < 16; ++ii) {
    const size_t oidx = base + (size_t)(i0 + ii) * stride_j + d0;
    float a0 = acc[ii].x, a1 = acc[ii].y;
    if (FUSE) {
      bf16x2 uu = *(const bf16x2*)(ufuse + oidx);
      a0 *= (float)uu[0];
      a1 *= (float)uu[1];
    }
    bf16x2 o2 = {(bf16)a0, (bf16)a1};
    *(bf16x2*)(out + oidx) = o2;
  }
}

// ---------------- launch ----------------

extern "C" void kernel_launch(void* const* d_in, const int* in_sizes, int n_in,
                              void* d_out, int out_size, void* d_ws, size_t ws_size,
                              hipStream_t stream) {
  const float* x    = (const float*)d_in[0];
  const float* u_w  = (const float*)d_in[1];
  const float* u_b  = (const float*)d_in[2];
  const float* v_w  = (const float*)d_in[3];
  const float* v_b  = (const float*)d_in[4];
  const float* o_w  = (const float*)d_in[5];
  const float* o_b  = (const float*)d_in[6];
  const float* t1z  = (const float*)d_in[7];
  const float* t1pa = (const float*)d_in[8];
  const float* t1pb = (const float*)d_in[9];
  const float* t1na = (const float*)d_in[10];
  const float* t1nb = (const float*)d_in[11];
  const float* t2z  = (const float*)d_in[12];
  const float* t2pa = (const float*)d_in[13];
  const float* t2pb = (const float*)d_in[14];
  const float* t2na = (const float*)d_in[15];
  const float* t2nb = (const float*)d_in[16];

  char* ws = (char*)d_ws;
  size_t off = 0;
  auto alloc = [&](size_t bytes) {
    char* p = ws + off;
    off += (bytes + 255) & ~(size_t)255;
    return p;
  };
  bf16*  xb   = (bf16*)alloc(32768ull * 512 * 2);
  bf16*  wuv  = (bf16*)alloc(2048ull * 512 * 2);
  bf16*  owb  = (bf16*)alloc(512ull * 1024 * 2);
  float* buv  = (float*)alloc(2048ull * 4);
  unsigned int* Tkp1 = (unsigned int*)alloc(8ull * 127 * 64 * 4);
  unsigned int* Tkp2 = (unsigned int*)alloc(8ull * 127 * 64 * 4);
  bf16*  u    = (bf16*)alloc(32768ull * 1024 * 2);
  bf16*  v    = (bf16*)alloc(32768ull * 1024 * 2);
  bf16*  tmid = (bf16*)alloc(32768ull * 1024 * 2);
  bf16*  g    = v;   // v dead after pass1; reuse for gate output

  cast_f32_to_bf16<<<16384, 256, 0, stream>>>(x, xb, 16777216 / 4);
  cast_f32_to_bf16<<<512, 256, 0, stream>>>(u_w, wuv, 524288 / 4);
  cast_f32_to_bf16<<<512, 256, 0, stream>>>(v_w, wuv + 524288, 524288 / 4);
  cast_f32_to_bf16<<<512, 256, 0, stream>>>(o_w, owb, 524288 / 4);
  concat_bias<<<4, 256, 0, stream>>>(u_b, v_b, buv);
  build_tkp<<<254, 256, 0, stream>>>(t1z, t1pa, t1pb, t1na, t1nb, Tkp1, 1.0f);
  build_tkp<<<254, 256, 0, stream>>>(t2z, t2pa, t2pb, t2na, t2nb, Tkp2, 2.0f);  // x2 folded

  gemm_bt<0><<<4096, 256, 0, stream>>>(xb, wuv, buv, u, v, nullptr, 32768, 2048, 512);
  toep_pass<0><<<4096, 256, 0, stream>>>(v, Tkp1, nullptr, tmid, 1024, 65536);
  toep_pass<1><<<4096, 256, 0, stream>>>(tmid, Tkp2, u, g, 65536, 1024);
  gemm_bt<1><<<1024, 256, 0, stream>>>(g, owb, o_b, nullptr, nullptr, (float*)d_out,
                                       32768, 512, 1024);
}

// Round 3
// 309.004 us; speedup vs baseline: 1.7312x; 1.2805x over previous
//
#include <hip/hip_runtime.h>
#include <hip/hip_bf16.h>
#include <hip/hip_fp16.h>

typedef __bf16 bf16;
typedef bf16 bf16x2 __attribute__((ext_vector_type(2)));
typedef bf16 bf16x4 __attribute__((ext_vector_type(4)));
typedef bf16 bf16x8 __attribute__((ext_vector_type(8)));
typedef float f32x2 __attribute__((ext_vector_type(2)));
typedef float f32x4 __attribute__((ext_vector_type(4)));

__device__ __forceinline__ void gload_lds16(const void* g, void* l) {
  __builtin_amdgcn_global_load_lds((__attribute__((address_space(1))) void*)g,
                                   (__attribute__((address_space(3))) void*)l,
                                   16, 0, 0);
}

__device__ __forceinline__ f32x2 fma2(f32x2 a, f32x2 b, f32x2 c) {
  return __builtin_elementwise_fma(a, b, c);   // -> v_pk_fma_f32
}

__device__ __forceinline__ f32x2 cvt2(unsigned int u) {
  __half2 h = *(__half2*)&u;
  float2 f = __half22float2(h);
  f32x2 r = {f.x, f.y};
  return r;
}

// ---------------- prep kernels ----------------

__global__ void cast_f32_to_bf16(const float* __restrict__ in, bf16* __restrict__ out, int n4) {
  int i = blockIdx.x * blockDim.x + threadIdx.x;
  if (i >= n4) return;
  float4 v = ((const float4*)in)[i];
  bf16x4 o = {(bf16)v.x, (bf16)v.y, (bf16)v.z, (bf16)v.w};
  ((bf16x4*)out)[i] = o;
}

// three 524288-elem f32->bf16 casts in one launch; 131072 x4-threads per region
__global__ void cast_w3(const float* __restrict__ uw, const float* __restrict__ vw,
                        const float* __restrict__ ow,
                        bf16* __restrict__ wuv, bf16* __restrict__ owb) {
  int t = blockIdx.x * 256 + threadIdx.x;      // [0, 393216)
  int r = t >> 17;                             // region
  int i = t & 131071;
  const float* src = (r == 0) ? uw : (r == 1) ? vw : ow;
  bf16* dst = (r == 2) ? owb : (wuv + (r == 1) * 524288);
  float4 v = ((const float4*)src)[i];
  bf16x4 o = {(bf16)v.x, (bf16)v.y, (bf16)v.z, (bf16)v.w};
  ((bf16x4*)dst)[i] = o;
}

__global__ void concat_bias(const float* __restrict__ ub, const float* __restrict__ vb,
                            float* __restrict__ buv) {
  int i = blockIdx.x * blockDim.x + threadIdx.x;
  if (i < 1024) { buv[i] = ub[i]; buv[1024 + i] = vb[i]; }
}

// Toeplitz table, f16 channel-pair packed: Tkp[h][lag+63][cpair] (u32 = 2 f16).
__global__ void build_tkp(const float* __restrict__ zero, const float* __restrict__ pa,
                          const float* __restrict__ pb, const float* __restrict__ na,
                          const float* __restrict__ nb, unsigned int* __restrict__ Tkp,
                          float scale) {
  int idx = blockIdx.x * blockDim.x + threadIdx.x;
  if (idx >= 8 * 127 * 64) return;
  int cp = idx & 63;
  int lagIdx = (idx >> 6) % 127;
  int h = idx / (64 * 127);
  int lag = lagIdx - 63;
  float t0, t1;
  if (lag == 0) {
    t0 = zero[h * 128 + 2 * cp];
    t1 = zero[h * 128 + 2 * cp + 1];
  } else {
    int k = lag > 0 ? lag : -lag;
    const float* A  = lag > 0 ? pa : na;
    const float* Bm = lag > 0 ? pb : nb;
    float pos_f = (float)(k - 1) * (15.0f / 62.0f);
    int lo = (int)floorf(pos_f);
    int hi = min(lo + 1, 15);
    float w = pos_f - (float)lo;
    float s0 = 0.f, s1 = 0.f;
    for (int r = 0; r < 32; ++r) {
      float c = (1.f - w) * A[(h * 16 + lo) * 32 + r] + w * A[(h * 16 + hi) * 32 + r];
      s0 += c * Bm[(h * 32 + r) * 128 + 2 * cp];
      s1 += c * Bm[(h * 32 + r) * 128 + 2 * cp + 1];
    }
    float dec = powf(0.999f, (float)k);
    t0 = s0 * dec;
    t1 = s1 * dec;
  }
  __half2 hv = __floats2half2_rn(t0 * scale, t1 * scale);
  Tkp[idx] = *(unsigned int*)&hv;
}

// ---------------- GEMM (m97-style 128x128, B^T input, XCD swizzle) ----------------

template<int MODE>
__global__ __launch_bounds__(256)
void gemm_bt(const bf16* __restrict__ A, const bf16* __restrict__ B,
             const float* __restrict__ bias,
             bf16* __restrict__ out_u, bf16* __restrict__ out_v,
             float* __restrict__ out_f,
             int M, int N, int K) {
  __shared__ bf16 As[128 * 32];
  __shared__ bf16 Bs[128 * 32];
  const int tid  = threadIdx.x;
  const int lane = tid & 63;
  const int nbn  = N >> 7;
  // XCD-aware bijective swizzle (gridDim.x % 8 == 0 for all our launches)
  const int cpx  = gridDim.x >> 3;
  const int swz  = (blockIdx.x & 7) * cpx + (blockIdx.x >> 3);
  const int br   = (swz / nbn) << 7;
  const int bc   = (swz % nbn) << 7;
  const int wub  = __builtin_amdgcn_readfirstlane(tid & 192);

  f32x4 acc[4][4] = {};

  auto stage = [&](int k0) {
#pragma unroll
    for (int r = 0; r < 2; ++r) {
      const int flat = r * 256 + tid;
      const int row  = flat >> 2;
      const int kc   = (flat & 3) << 3;
      gload_lds16(A + ((size_t)(br + row) * K + k0 + kc),
                  (char*)As + (size_t)(r * 256 + wub) * 16);
      gload_lds16(B + ((size_t)(bc + row) * K + k0 + kc),
                  (char*)Bs + (size_t)(r * 256 + wub) * 16);
    }
  };

  const int l15 = lane & 15;
  const int lk  = (lane >> 4) << 3;
  const int wr  = ((tid >> 7) & 1) << 6;
  const int wc  = ((tid >> 6) & 1) << 6;

  auto compute = [&]() {
    bf16x8 af[4], bfr[4];
#pragma unroll
    for (int m = 0; m < 4; ++m)
      af[m] = *(const bf16x8*)&As[(wr + m * 16 + l15) * 32 + lk];
#pragma unroll
    for (int n = 0; n < 4; ++n)
      bfr[n] = *(const bf16x8*)&Bs[(wc + n * 16 + l15) * 32 + lk];
#pragma unroll
    for (int m = 0; m < 4; ++m)
#pragma unroll
      for (int n = 0; n < 4; ++n)
        acc[m][n] = __builtin_amdgcn_mfma_f32_16x16x32_bf16(af[m], bfr[n], acc[m][n], 0, 0, 0);
  };

  stage(0);
  __syncthreads();
  for (int k0 = 32; k0 < K; k0 += 32) {
    compute();
    __syncthreads();
    stage(k0);
    __syncthreads();
  }
  compute();

  const int lr4 = (lane >> 4) << 2;
  if (MODE == 0) {
    const bool isU = (bc < 1024);
    bf16* outp = isU ? out_u : out_v;
#pragma unroll
    for (int m = 0; m < 4; ++m) {
#pragma unroll
      for (int n = 0; n < 4; ++n) {
        const int col  = bc + wc + n * 16 + l15;
        const int ocol = (bc & 1023) + wc + n * 16 + l15;
        const float bv = bias[col];
#pragma unroll
        for (int r = 0; r < 4; ++r) {
          const int row = br + wr + m * 16 + lr4 + r;
          float xv = acc[m][n][r] + bv;
          float s  = xv / (1.f + __expf(-xv));
          outp[(size_t)row * 1024 + ocol] = (bf16)s;
        }
      }
    }
  } else {
#pragma unroll
    for (int m = 0; m < 4; ++m) {
#pragma unroll
      for (int n = 0; n < 4; ++n) {
        const int col  = bc + wc + n * 16 + l15;
        const float bv = bias[col];
#pragma unroll
        for (int r = 0; r < 4; ++r) {
          const int row = br + wr + m * 16 + lr4 + r;
          out_f[(size_t)row * N + col] = acc[m][n][r] + bv;
        }
      }
    }
  }
}

// ---------------- Toeplitz pass v3: j-blocked static-window conv -------------
// Block: one image row (64 pos) x one head (128 ch). 4 waves; wave w owns
// i in [16w,16w+16), lane owns channel pair. Per j-block of 16: load 31-lag
// T window into regs (static indices), 16x16 unrolled v_pk_fma_f32.
// T table staged async via global_load_lds; all LDS reads 2-way-conflict-free.

template<int FUSE>
__global__ __launch_bounds__(256)
void toep_pass(const bf16* __restrict__ in, const unsigned int* __restrict__ Tkp,
               const bf16* __restrict__ ufuse, bf16* __restrict__ out,
               int stride_j, int stride_row) {
  __shared__ unsigned int tkl[8192];   // [lag+63][pair], 127*64 used (+pad)
  __shared__ bf16 vbuf[64 * 132];      // row-pad 132 for staging writes
  const int tid    = threadIdx.x;
  const int rowIdx = blockIdx.x >> 3;
  const int head   = blockIdx.x & 7;
  const size_t base = (size_t)(rowIdx >> 6) * 4194304
                    + (size_t)(rowIdx & 63) * stride_row + head * 128;

  // async-stage T table: 8192 u32 = 8 iters x (256 thr x 16B), linear dest
  {
    const unsigned int* tg = Tkp + head * 8128;   // 64-word over-read padded in alloc
    const int wub = __builtin_amdgcn_readfirstlane(tid & 192);
#pragma unroll
    for (int it = 0; it < 8; ++it) {
      const int flat = it * 256 + tid;
      gload_lds16(tg + flat * 4, (char*)tkl + (size_t)(it * 256 + wub) * 16);
    }
  }
  // reg-stage v row (64 j x 128 ch bf16), 256B contiguous per j
#pragma unroll
  for (int it = 0; it < 2; ++it) {
    int c  = it * 256 + tid;
    int j  = c >> 3;
    int cg = c & 7;
    const bf16* p = in + base + (size_t)j * stride_j + cg * 16;
    bf16x8 a0 = *(const bf16x8*)p;
    bf16x8 a1 = *(const bf16x8*)(p + 8);
    *(bf16x8*)&vbuf[j * 132 + cg * 16]     = a0;
    *(bf16x8*)&vbuf[j * 132 + cg * 16 + 8] = a1;
  }
  __syncthreads();

  const int lane = tid & 63;
  const int i0   = (tid >> 6) << 4;
  f32x2 acc[16] = {};

  for (int jb = 0; jb < 4; ++jb) {      // NOT unrolled: small code, reused t[] regs
    // T window: lag = i0 - 16*jb - 15 + s, s = 0..30; word (lag+63)*64 + lane
    f32x2 t[31];
    const int tbase = (i0 - 16 * jb + 48) * 64 + lane;
#pragma unroll
    for (int s = 0; s < 31; ++s) t[s] = cvt2(tkl[tbase + s * 64]);
#pragma unroll
    for (int jj = 0; jj < 16; ++jj) {
      unsigned int vu = *(const unsigned int*)&vbuf[(jb * 16 + jj) * 132 + (lane << 1)];
      f32x2 v2;
      v2.x = __uint_as_float(vu << 16);
      v2.y = __uint_as_float(vu & 0xFFFF0000u);
#pragma unroll
      for (int ii = 0; ii < 16; ++ii)
        acc[ii] = fma2(t[ii - jj + 15], v2, acc[ii]);
    }
  }

  const int d0 = lane << 1;
#pragma unroll
  for (int ii = 0; ii < 16; ++ii) {
    const size_t oidx = base + (size_t)(i0 + ii) * stride_j + d0;
    float a0 = acc[ii].x, a1 = acc[ii].y;
    if (FUSE) {
      bf16x2 uu = *(const bf16x2*)(ufuse + oidx);
      a0 *= (float)uu[0];
      a1 *= (float)uu[1];
    }
    bf16x2 o2 = {(bf16)a0, (bf16)a1};
    *(bf16x2*)(out + oidx) = o2;
  }
}

// ---------------- launch ----------------

extern "C" void kernel_launch(void* const* d_in, const int* in_sizes, int n_in,
                              void* d_out, int out_size, void* d_ws, size_t ws_size,
                              hipStream_t stream) {
  const float* x    = (const float*)d_in[0];
  const float* u_w  = (const float*)d_in[1];
  const float* u_b  = (const float*)d_in[2];
  const float* v_w  = (const float*)d_in[3];
  const float* v_b  = (const float*)d_in[4];
  const float* o_w  = (const float*)d_in[5];
  const float* o_b  = (const float*)d_in[6];
  const float* t1z  = (const float*)d_in[7];
  const float* t1pa = (const float*)d_in[8];
  const float* t1pb = (const float*)d_in[9];
  const float* t1na = (const float*)d_in[10];
  const float* t1nb = (const float*)d_in[11];
  const float* t2z  = (const float*)d_in[12];
  const float* t2pa = (const float*)d_in[13];
  const float* t2pb = (const float*)d_in[14];
  const float* t2na = (const float*)d_in[15];
  const float* t2nb = (const float*)d_in[16];

  char* ws = (char*)d_ws;
  size_t off = 0;
  auto alloc = [&](size_t bytes) {
    char* p = ws + off;
    off += (bytes + 255) & ~(size_t)255;
    return p;
  };
  bf16*  xb   = (bf16*)alloc(32768ull * 512 * 2);
  bf16*  wuv  = (bf16*)alloc(2048ull * 512 * 2);
  bf16*  owb  = (bf16*)alloc(512ull * 1024 * 2);
  float* buv  = (float*)alloc(2048ull * 4);
  unsigned int* Tkp1 = (unsigned int*)alloc(8ull * 127 * 64 * 4 + 256);  // +over-read pad
  unsigned int* Tkp2 = (unsigned int*)alloc(8ull * 127 * 64 * 4 + 256);
  bf16*  u    = (bf16*)alloc(32768ull * 1024 * 2);
  bf16*  v    = (bf16*)alloc(32768ull * 1024 * 2);
  bf16*  tmid = (bf16*)alloc(32768ull * 1024 * 2);
  bf16*  g    = v;   // v dead after pass1; reuse for gate output

  cast_f32_to_bf16<<<16384, 256, 0, stream>>>(x, xb, 16777216 / 4);
  cast_w3<<<1536, 256, 0, stream>>>(u_w, v_w, o_w, wuv, owb);
  concat_bias<<<4, 256, 0, stream>>>(u_b, v_b, buv);
  build_tkp<<<254, 256, 0, stream>>>(t1z, t1pa, t1pb, t1na, t1nb, Tkp1, 1.0f);
  build_tkp<<<254, 256, 0, stream>>>(t2z, t2pa, t2pb, t2na, t2nb, Tkp2, 2.0f);  // x2 folded

  gemm_bt<0><<<4096, 256, 0, stream>>>(xb, wuv, buv, u, v, nullptr, 32768, 2048, 512);
  toep_pass<0><<<4096, 256, 0, stream>>>(v, Tkp1, nullptr, tmid, 1024, 65536);
  toep_pass<1><<<4096, 256, 0, stream>>>(tmid, Tkp2, u, g, 65536, 1024);
  gemm_bt<1><<<1024, 256, 0, stream>>>(g, owb, o_b, nullptr, nullptr, (float*)d_out,
                                       32768, 512, 1024);
}